// Round 4
// baseline (477.454 us; speedup 1.0000x reference)
//
#include <hip/hip_runtime.h>
#include <math.h>

// Problem constants (B=1)
#define MM 1024
#define DD 512
#define CC 128
#define LDSR 516   // A row stride in ushorts: 1032 B = 258 dw ≡ 2 (mod 32)
                   // -> lane start-bank 2l mod 32: 2-way = free (m136). 8B-aligned rows.

// ws layout (floats):
//  H[1024][3072]      @ 0        (0..1023 ms-hidden, 1024..2047 src_proj; 2048+ unused now)
//  slow[1024][128]    @ 3145728
//  spk_proj[2][1024]  @ 3276800
//  bkt_proj[10][1024] @ 3278848
//  ms[1024]           @ 3289088
//  lossp[1024]        @ 3290112
//  embb bf16[1024][512]  @ 3291136
//  Wall bf16[4096][512]  @ 3553280
//    rows [0,1024)=ms_W0^T, [1024,2048)=W_src^T
//    rows [2048,3072) reused as WfragAnt (fragment-major W_ant)
//    rows [3072,4096) reused as Wfrag (fragment-major W_prod)
//  frag layout: [tile t:32][kstep s:32][lane:64][8] bf16
//    element (f = t*32 + (lane&31), k = s*16 + (lane>>5)*8 + j) at ((t*32+s)*64+lane)*8+j

typedef __attribute__((ext_vector_type(8))) short bf16x8;
typedef __attribute__((ext_vector_type(4), aligned(8))) short bf16x4a;
typedef __attribute__((ext_vector_type(4))) float f32x4;
typedef __attribute__((ext_vector_type(16))) float f32x16;

__device__ __forceinline__ ushort bf16_rn(float x) {
    uint u = __float_as_uint(x);
    uint r = u + 0x7fffu + ((u >> 16) & 1u);
    return (ushort)(r >> 16);
}
__device__ __forceinline__ float bf16_to_f(ushort u) {
    return __uint_as_float(((uint)u) << 16);
}
__device__ __forceinline__ bf16x8 ld_lds16(const ushort* p) {   // two ds_read_b64
    bf16x4a lo = *(const bf16x4a*)p;
    bf16x4a hi = *(const bf16x4a*)(p + 4);
    return __builtin_shufflevector(lo, hi, 0, 1, 2, 3, 4, 5, 6, 7);
}

// ---------------- prep: emb fp32 -> bf16
__global__ __launch_bounds__(256) void prep_emb(const float* __restrict__ emb,
                                                ushort* __restrict__ embb)
{
    int i = blockIdx.x * 256 + threadIdx.x;
    float2 v = ((const float2*)emb)[i];
    ushort2 o;
    o.x = bf16_rn(v.x);
    o.y = bf16_rn(v.y);
    ((ushort2*)embb)[i] = o;
}

// ---------------- prep: transpose+convert W0 blocks 0..1 -> Wall[2048 n][512 k] bf16
__global__ __launch_bounds__(256) void prep_wall(const float* __restrict__ ms_W0,
                                                 const float* __restrict__ sp_W0,
                                                 ushort* __restrict__ Wall)
{
    __shared__ float t[64][65];
    const int k0 = blockIdx.x * 64;   // 8
    const int n0 = blockIdx.y * 64;   // 32 (rows 0..2047 only)
    const int g = n0 >> 10;
    const float* src = (g == 0) ? ms_W0 : (sp_W0 + (size_t)(g - 1) * 512 * 1024);
    const int col0 = n0 & 1023;
    const int tr = threadIdx.x >> 6, tc = threadIdx.x & 63;
#pragma unroll
    for (int i = 0; i < 16; ++i) {
        int k = tr + i * 4;
        t[k][tc] = src[(size_t)(k0 + k) * 1024 + col0 + tc];
    }
    __syncthreads();
    const int f = threadIdx.x >> 2;
    const int c4 = threadIdx.x & 3;
    ushort tmp[16];
#pragma unroll
    for (int j = 0; j < 16; ++j) tmp[j] = bf16_rn(t[c4 * 16 + j][f]);
    uint4* dst = (uint4*)(Wall + (size_t)(n0 + f) * 512 + k0 + c4 * 16);
    dst[0] = *(uint4*)&tmp[0];
    dst[1] = *(uint4*)&tmp[8];
}

// ---------------- prep: W [k=512][f=1024] -> fragment-major (wave load = contiguous 1 KB)
__global__ __launch_bounds__(64) void prep_wfrag(const float* __restrict__ W,
                                                 ushort* __restrict__ dst_frag)
{
    const int ts = blockIdx.x;            // t*32 + s, 0..1023
    const int l = threadIdx.x;            // 0..63
    const int tt = ts >> 5, s = ts & 31;
    const int f = tt * 32 + (l & 31);
    const int kb = s * 16 + (l >> 5) * 8;
    ushort tmp[8];
#pragma unroll
    for (int j = 0; j < 8; ++j) tmp[j] = bf16_rn(W[(size_t)(kb + j) * 1024 + f]);
    uint4* dst = (uint4*)(dst_frag + ((size_t)ts * 64 + l) * 8);
    *dst = *(uint4*)&tmp[0];
}

// ---------------- H = emb @ [ms_W0 | W_src] via MFMA (1024x512x2048)
__global__ __launch_bounds__(256) void gemm_h_mfma(
    const ushort* __restrict__ embb, const ushort* __restrict__ Wall,
    float* __restrict__ H)
{
    const int n0 = blockIdx.x * 128;  // 16
    const int m0 = blockIdx.y * 128;  // 8
    const int lane = threadIdx.x & 63, wave = threadIdx.x >> 6;
    const int wx = wave & 1, wy = wave >> 1;
    const int l15 = lane & 15, lq = lane >> 4;

    const ushort* arow[4];
#pragma unroll
    for (int mi = 0; mi < 4; ++mi)
        arow[mi] = embb + (size_t)(m0 + wy * 64 + mi * 16 + l15) * 512;
    const ushort* brow[4];
#pragma unroll
    for (int ni = 0; ni < 4; ++ni)
        brow[ni] = Wall + (size_t)(n0 + wx * 64 + ni * 16 + l15) * 512;

    f32x4 acc[4][4];
#pragma unroll
    for (int i = 0; i < 4; ++i)
#pragma unroll
        for (int j = 0; j < 4; ++j) acc[i][j] = (f32x4)0.f;

    for (int kt = 0; kt < 512; kt += 32) {
        const int ko = kt + lq * 8;
        bf16x8 av[4], bv[4];
#pragma unroll
        for (int mi = 0; mi < 4; ++mi) av[mi] = *(const bf16x8*)(arow[mi] + ko);
#pragma unroll
        for (int ni = 0; ni < 4; ++ni) bv[ni] = *(const bf16x8*)(brow[ni] + ko);
#pragma unroll
        for (int mi = 0; mi < 4; ++mi)
#pragma unroll
            for (int ni = 0; ni < 4; ++ni)
                acc[mi][ni] = __builtin_amdgcn_mfma_f32_16x16x32_bf16(av[mi], bv[ni], acc[mi][ni], 0, 0, 0);
    }
#pragma unroll
    for (int mi = 0; mi < 4; ++mi)
#pragma unroll
        for (int r = 0; r < 4; ++r) {
            int mrow = m0 + wy * 64 + mi * 16 + lq * 4 + r;
#pragma unroll
            for (int ni = 0; ni < 4; ++ni)
                H[(size_t)mrow * 3072 + n0 + wx * 64 + ni * 16 + l15] = acc[mi][ni][r];
        }
}

// ---------------- small projections
__global__ void small_proj(const float* __restrict__ speaker_emb,
                           const float* __restrict__ bucket_emb,
                           const float* __restrict__ sp_W0,
                           float* __restrict__ spk_proj, float* __restrict__ bkt_proj)
{
    int r = blockIdx.x; // 0..11
    const float* e; const float* W; float* out;
    if (r < 2) { e = speaker_emb + r * 20; W = sp_W0 + (size_t)1536 * 1024; out = spk_proj + r * 1024; }
    else       { e = bucket_emb + (r - 2) * 20; W = sp_W0 + (size_t)1556 * 1024; out = bkt_proj + (r - 2) * 1024; }
    float ek[20];
#pragma unroll
    for (int k = 0; k < 20; ++k) ek[k] = e[k];
    for (int f = threadIdx.x; f < 1024; f += blockDim.x) {
        float s = 0.f;
#pragma unroll
        for (int k = 0; k < 20; ++k) s = fmaf(ek[k], W[(size_t)k * 1024 + f], s);
        out[f] = s;
    }
}

// ---------------- mention scores
__global__ __launch_bounds__(256) void mention_score(
    const float* __restrict__ H, const float* __restrict__ ms_b0,
    const float* __restrict__ ms_W1, const float* __restrict__ ms_b1,
    float* __restrict__ ms)
{
    int m = blockIdx.x;
    float v = 0.f;
    for (int f = threadIdx.x; f < 1024; f += 256) {
        float h = H[(size_t)m * 3072 + f] + ms_b0[f];
        v += fmaxf(h, 0.f) * ms_W1[f];
    }
#pragma unroll
    for (int o = 1; o < 64; o <<= 1) v += __shfl_xor(v, o);
    __shared__ float sm[4];
    if ((threadIdx.x & 63) == 0) sm[threadIdx.x >> 6] = v;
    __syncthreads();
    if (threadIdx.x == 0) ms[m] = sm[0] + sm[1] + sm[2] + sm[3] + ms_b1[0];
}

// ---------------- pair scorer v5: ONE dispatch, grid (1024 m, 4 = chalf + 2*fh).
// 512 threads / 8 waves, LDS A-tile 64 x 512 (68.6 KB) -> 2 blocks/CU.
// Two k-loop phases accumulating into the same AGPR acc:
//   phase 1: A = bf16(em*ea) products, B = W_prod fragments  (src*ant term)
//   phase 2: A = ea rows (pure copy), B = W_ant fragments    (ant term, folded:
//            replaces the 64 latency-chained per-c H-row gathers in the epilogue)
// Epilogue keeps only srcb + speaker select + 10-row bucket table (L1-hot).
// f-half partials combined via atomicAdd onto zeroed slow (2 adds onto 0: exact).
__global__ __launch_bounds__(512, 4) void pair_mfma(
    const ushort* __restrict__ embb, const ushort* __restrict__ Wfrag,
    const ushort* __restrict__ WfragAnt,
    const float* __restrict__ H, const float* __restrict__ spk_proj,
    const float* __restrict__ bkt_proj, const float* __restrict__ sp_b0,
    const float* __restrict__ sp_W1, const int* __restrict__ speaker,
    float* __restrict__ slow)
{
    extern __shared__ ushort Alds[];                  // 64*LDSR ushorts
    float* red = (float*)(Alds + 64 * LDSR);          // 8*64 floats
    int* meta_ss = (int*)(red + 8 * 64);              // 64 ints
    int* meta_bk = meta_ss + 64;                      // 64 ints
    const int m = blockIdx.x;
    const int cbase = (blockIdx.y & 1) * 64;          // runtime: 0 or 64
    const int fh = blockIdx.y >> 1;                   // 0 or 1 (f-half), slow grid dim
    const int tid = threadIdx.x;
    const int spk_m = speaker[m];

    const int cA = tid >> 3;                          // 0..63 (A-build row)
    const int khA = (tid & 7) * 64;
    int aA = m - 1 - (cbase + cA); if (aA < 0) aA = 0;
    const ushort* eaA = embb + (size_t)aA * 512 + khA;
    ushort* dstA = Alds + cA * LDSR + khA;

    // ---- phase-1 A build: A[c][k] = bf16(em[k]*ea[k]) + per-c metadata
    {
        const ushort* em = embb + (size_t)m * 512 + khA;
#pragma unroll
        for (int j = 0; j < 64; j += 8) {
            bf16x8 va = *(const bf16x8*)(eaA + j);
            bf16x8 vm = *(const bf16x8*)(em + j);
            uint pr[4];
#pragma unroll
            for (int p = 0; p < 4; ++p) {
                float q0 = bf16_to_f((ushort)va[2 * p])     * bf16_to_f((ushort)vm[2 * p]);
                float q1 = bf16_to_f((ushort)va[2 * p + 1]) * bf16_to_f((ushort)vm[2 * p + 1]);
                pr[p] = __builtin_amdgcn_perm(__float_as_uint(q1), __float_as_uint(q0), 0x07060302u);
            }
            *(uint2*)(dstA + j)     = *(uint2*)&pr[0];   // 8B stores (rows are 8B-aligned)
            *(uint2*)(dstA + j + 4) = *(uint2*)&pr[2];
        }
        if ((tid & 7) == 0) {
            meta_ss[cA] = (speaker[aA] == spk_m) ? 1 : 0;
            int off = cbase + cA + 1;                  // 1..128
            int bk;
            if (off <= 4) bk = off;
            else { bk = 31 - __clz(off) + 3; if (bk > 9) bk = 9; }
            meta_bk[cA] = bk;                          // cbase=64 -> uniformly 9
        }
    }
    __syncthreads();

    const int lane = tid & 63;
    const int wave = __builtin_amdgcn_readfirstlane(tid >> 6);   // 0..7, wave-uniform
    const int l31 = lane & 31, k5 = lane >> 5;
    const ushort* ab = Alds + l31 * LDSR + k5 * 8;

    f32x16 acc[2][2];
#pragma unroll
    for (int i = 0; i < 2; ++i)
#pragma unroll
        for (int j = 0; j < 2; ++j) acc[i][j] = (f32x16)0.f;

    // ---- k-loop phase 1: src*ant term (B = W_prod fragments)
    {
        const ushort* bb = Wfrag + (size_t)(fh * 16 + wave * 2) * 16384 + (size_t)lane * 8;
#pragma unroll 2
        for (int s = 0; s < 32; ++s) {
            bf16x8 b0 = *(const bf16x8*)(bb + s * 512);
            bf16x8 b1 = *(const bf16x8*)(bb + 16384 + s * 512);
            bf16x8 a0 = ld_lds16(ab + s * 16);
            bf16x8 a1 = ld_lds16(ab + 32 * LDSR + s * 16);
            acc[0][0] = __builtin_amdgcn_mfma_f32_32x32x16_bf16(a0, b0, acc[0][0], 0, 0, 0);
            acc[0][1] = __builtin_amdgcn_mfma_f32_32x32x16_bf16(a0, b1, acc[0][1], 0, 0, 0);
            acc[1][0] = __builtin_amdgcn_mfma_f32_32x32x16_bf16(a1, b0, acc[1][0], 0, 0, 0);
            acc[1][1] = __builtin_amdgcn_mfma_f32_32x32x16_bf16(a1, b1, acc[1][1], 0, 0, 0);
        }
    }
    __syncthreads();   // all waves done reading phase-1 A

    // ---- phase-2 A build: pure copy A[c][k] = ea[k]
    {
#pragma unroll
        for (int j = 0; j < 64; j += 16) {
            bf16x8 v0 = *(const bf16x8*)(eaA + j);
            bf16x8 v1 = *(const bf16x8*)(eaA + j + 8);
            *(uint2*)(dstA + j)      = *(uint2*)&v0;
            *(uint2*)(dstA + j + 4)  = *((uint2*)&v0 + 1);
            *(uint2*)(dstA + j + 8)  = *(uint2*)&v1;
            *(uint2*)(dstA + j + 12) = *((uint2*)&v1 + 1);
        }
    }
    __syncthreads();

    // ---- k-loop phase 2: ant term (B = W_ant fragments), same acc
    {
        const ushort* bb = WfragAnt + (size_t)(fh * 16 + wave * 2) * 16384 + (size_t)lane * 8;
#pragma unroll 2
        for (int s = 0; s < 32; ++s) {
            bf16x8 b0 = *(const bf16x8*)(bb + s * 512);
            bf16x8 b1 = *(const bf16x8*)(bb + 16384 + s * 512);
            bf16x8 a0 = ld_lds16(ab + s * 16);
            bf16x8 a1 = ld_lds16(ab + 32 * LDSR + s * 16);
            acc[0][0] = __builtin_amdgcn_mfma_f32_32x32x16_bf16(a0, b0, acc[0][0], 0, 0, 0);
            acc[0][1] = __builtin_amdgcn_mfma_f32_32x32x16_bf16(a0, b1, acc[0][1], 0, 0, 0);
            acc[1][0] = __builtin_amdgcn_mfma_f32_32x32x16_bf16(a1, b0, acc[1][0], 0, 0, 0);
            acc[1][1] = __builtin_amdgcn_mfma_f32_32x32x16_bf16(a1, b1, acc[1][1], 0, 0, 0);
        }
    }

    // ---- epilogue (no per-c H gathers anymore)
    const int f0 = fh * 512 + wave * 64;
    float srcb[2], w1v[2], sp0v[2], sp1v[2];
#pragma unroll
    for (int ni = 0; ni < 2; ++ni) {
        int fcol = f0 + ni * 32 + l31;
        srcb[ni] = H[(size_t)m * 3072 + 1024 + fcol] + sp_b0[fcol];
        w1v[ni]  = sp_W1[fcol];
        sp0v[ni] = spk_proj[fcol];
        sp1v[ni] = spk_proj[1024 + fcol];
    }
    // C/D 32x32 layout: col=lane&31, row=(reg&3)+8*(reg>>2)+4*(lane>>5)
#pragma unroll
    for (int mi = 0; mi < 2; ++mi) {
#pragma unroll
        for (int reg = 0; reg < 16; ++reg) {
            const int c = mi * 32 + 4 * k5 + (reg & 3) + 8 * (reg >> 2);  // local
            const int ss = meta_ss[c];
            const int bk = meta_bk[c];
            float s = 0.f;
#pragma unroll
            for (int ni = 0; ni < 2; ++ni) {
                const int fcol = f0 + ni * 32 + l31;
                float bval = bkt_proj[(size_t)bk * 1024 + fcol];   // 40 KB table, L1-hot
                float pre = acc[mi][ni][reg] + srcb[ni] + (ss ? sp1v[ni] : sp0v[ni]) + bval;
                s += fmaxf(pre, 0.f) * w1v[ni];
            }
            s += __shfl_xor(s, 1); s += __shfl_xor(s, 2); s += __shfl_xor(s, 4);
            s += __shfl_xor(s, 8); s += __shfl_xor(s, 16);
            if (l31 == 0) red[wave * 64 + c] = s;
        }
    }
    __syncthreads();
    if (tid < 64) {
        float s = 0.f;
#pragma unroll
        for (int i = 0; i < 8; ++i) s += red[i * 64 + tid];
        atomicAdd(slow + (size_t)m * 128 + cbase + tid, s);
    }
}

// ---------------- softmax + per-mention loss
__device__ __forceinline__ float bsum2(float v, float* sm) {
#pragma unroll
    for (int o = 1; o < 64; o <<= 1) v += __shfl_xor(v, o);
    __syncthreads();
    if ((threadIdx.x & 63) == 0) sm[threadIdx.x >> 6] = v;
    __syncthreads();
    return sm[0] + sm[1];
}
__device__ __forceinline__ float bmax2(float v, float* sm) {
#pragma unroll
    for (int o = 1; o < 64; o <<= 1) v = fmaxf(v, __shfl_xor(v, o));
    __syncthreads();
    if ((threadIdx.x & 63) == 0) sm[threadIdx.x >> 6] = v;
    __syncthreads();
    return fmaxf(sm[0], sm[1]);
}

__global__ __launch_bounds__(128) void softmax_loss(
    const float* __restrict__ slow, const float* __restrict__ ms,
    const float* __restrict__ sp_b1, const int* __restrict__ cluster,
    float* __restrict__ out, float* __restrict__ loss_partial)
{
    const int m = blockIdx.x, c = threadIdx.x;
    __shared__ float sm[2];
    const int raw = m - 1 - c;
    const bool maskv = raw >= 0;
    const int a = maskv ? raw : 0;
    float score = slow[(size_t)m * 128 + c] + sp_b1[0] + ms[m] + ms[a];
    if (!maskv) score = -INFINITY;

    float mx = fmaxf(bmax2(score, sm), 0.f);
    float e = expf(score - mx);
    float e0 = expf(0.f - mx);
    float sum = bsum2(e, sm) + e0;
    float p = e / sum, p0 = e0 / sum;
    const float eps = 1e-6f;
    p  = fminf(fmaxf(p,  eps), 1.f - eps);
    p0 = fminf(fmaxf(p0, eps), 1.f - eps);
    float sum2 = bsum2(p, sm) + p0;
    p /= sum2; p0 /= sum2;
    out[(size_t)m * 129 + 1 + c] = p;
    if (c == 0) out[(size_t)m * 129] = p0;

    const int cid = cluster[m];
    const bool lbl = maskv && (cid > 0) && (cluster[a] == cid);
    float anyc = bsum2(lbl ? 1.f : 0.f, sm);
    float lsum = bsum2(lbl ? -logf(p) : 0.f, sm);
    if (c == 0) {
        if (anyc == 0.f) lsum += -logf(p0);
        loss_partial[m] = lsum;
    }
}

__global__ void loss_sum(const float* __restrict__ lp, float* __restrict__ out) {
    float v = 0.f;
    for (int i = threadIdx.x; i < 1024; i += 256) v += lp[i];
#pragma unroll
    for (int o = 1; o < 64; o <<= 1) v += __shfl_xor(v, o);
    __shared__ float sm[4];
    if ((threadIdx.x & 63) == 0) sm[threadIdx.x >> 6] = v;
    __syncthreads();
    if (threadIdx.x == 0) out[(size_t)1024 * 129] = sm[0] + sm[1] + sm[2] + sm[3];
}

extern "C" void kernel_launch(void* const* d_in, const int* in_sizes, int n_in,
                              void* d_out, int out_size, void* d_ws, size_t ws_size,
                              hipStream_t stream)
{
    const float* emb   = (const float*)d_in[0];
    const int*   clus  = (const int*)  d_in[1];
    const int*   spk   = (const int*)  d_in[2];
    const float* ms_W0 = (const float*)d_in[3];
    const float* ms_b0 = (const float*)d_in[4];
    const float* ms_W1 = (const float*)d_in[5];
    const float* ms_b1 = (const float*)d_in[6];
    const float* sp_W0 = (const float*)d_in[7];
    const float* sp_b0 = (const float*)d_in[8];
    const float* sp_W1 = (const float*)d_in[9];
    const float* sp_b1 = (const float*)d_in[10];
    const float* spke  = (const float*)d_in[11];
    const float* bkte  = (const float*)d_in[12];

    float* ws = (float*)d_ws;
    float* H        = ws;
    float* slow     = ws + 3145728;
    float* spk_proj = ws + 3276800;
    float* bkt_proj = ws + 3278848;
    float* msc      = ws + 3289088;
    float* lossp    = ws + 3290112;
    ushort* embb    = (ushort*)(ws + 3291136);
    ushort* Wall    = (ushort*)(ws + 3553280);
    ushort* WfragAnt= Wall + (size_t)2048 * 512;   // reuse dead W_ant^T region
    ushort* Wfrag   = Wall + (size_t)3072 * 512;   // reuse W_prod region, frag-major
    float* out = (float*)d_out;

    const int pair_lds = 64 * LDSR * 2 + 8 * 64 * 4 + 2 * 64 * 4;   // 68608 B

    static bool attr_set = false;
    if (!attr_set) {
        hipFuncSetAttribute((const void*)&pair_mfma,
                            hipFuncAttributeMaxDynamicSharedMemorySize,
                            pair_lds);
        attr_set = true;
    }

    hipMemsetAsync(slow, 0, (size_t)1024 * 128 * sizeof(float), stream);
    hipLaunchKernelGGL(prep_emb, dim3(1024), dim3(256), 0, stream, emb, embb);
    hipLaunchKernelGGL(prep_wall, dim3(8, 32), dim3(256), 0, stream, ms_W0, sp_W0, Wall);
    hipLaunchKernelGGL(prep_wfrag, dim3(1024), dim3(64), 0, stream,
                       sp_W0 + (size_t)1024 * 1024, Wfrag);     // W_prod
    hipLaunchKernelGGL(prep_wfrag, dim3(1024), dim3(64), 0, stream,
                       sp_W0 + (size_t)512 * 1024, WfragAnt);   // W_ant
    hipLaunchKernelGGL(gemm_h_mfma, dim3(16, 8), dim3(256), 0, stream, embb, Wall, H);
    hipLaunchKernelGGL(small_proj, dim3(12), dim3(256), 0, stream, spke, bkte, sp_W0, spk_proj, bkt_proj);
    hipLaunchKernelGGL(mention_score, dim3(1024), dim3(256), 0, stream, H, ms_b0, ms_W1, ms_b1, msc);
    hipLaunchKernelGGL(pair_mfma, dim3(1024, 4), dim3(512), pair_lds, stream,
                       embb, Wfrag, WfragAnt, H, spk_proj, bkt_proj, sp_b0, sp_W1, spk, slow);
    hipLaunchKernelGGL(softmax_loss, dim3(1024), dim3(128), 0, stream,
                       slow, msc, sp_b1, clus, out, lossp);
    hipLaunchKernelGGL(loss_sum, dim3(1), dim3(256), 0, stream, lossp, out);
}

// Round 5
// 367.295 us; speedup vs baseline: 1.2999x; 1.2999x over previous
//
#include <hip/hip_runtime.h>
#include <math.h>

// Problem constants (B=1)
#define MM 1024
#define DD 512
#define CC 128
#define LDSR 516   // A row stride in ushorts: 1032 B = 258 dw ≡ 2 (mod 32)
                   // -> lane start-bank 2l mod 32: 2-way = free (m136). 8B-aligned rows.

// ws layout (floats):
//  H[1024][3072]      @ 0        (0..1023 ms-hidden, 1024.. src_proj, 2048.. ant_proj)
//  slow0[1024][128]   @ 3145728  (fh=0 partials)
//  spk_proj[2][1024]  @ 3276800
//  bkt_proj[10][1024] @ 3278848
//  ms[1024]           @ 3289088
//  lossp[1024]        @ 3290112
//  embb bf16[1024][512]  @ 3291136
//  Wall bf16[4096][512]  @ 3553280
//    rows [0,1024)=ms_W0^T, [1024,2048)=W_src^T, [2048,3072)=W_ant^T
//    region [3072,4096) reused as Wfrag: [tile t:32][kstep s:32][lane:64][8] bf16
//      element (f = t*32 + (lane&31), k = s*16 + (lane>>5)*8 + j) at ((t*32+s)*64+lane)*8+j
//  slow1[1024][128]   @ 4601856  (fh=1 partials)

typedef __attribute__((ext_vector_type(8))) short bf16x8;
typedef __attribute__((ext_vector_type(4), aligned(8))) short bf16x4a;
typedef __attribute__((ext_vector_type(4))) float f32x4;
typedef __attribute__((ext_vector_type(16))) float f32x16;

__device__ __forceinline__ ushort bf16_rn(float x) {
    uint u = __float_as_uint(x);
    uint r = u + 0x7fffu + ((u >> 16) & 1u);
    return (ushort)(r >> 16);
}
__device__ __forceinline__ float bf16_to_f(ushort u) {
    return __uint_as_float(((uint)u) << 16);
}
__device__ __forceinline__ bf16x8 ld_lds16(const ushort* p) {   // two ds_read_b64
    bf16x4a lo = *(const bf16x4a*)p;
    bf16x4a hi = *(const bf16x4a*)(p + 4);
    return __builtin_shufflevector(lo, hi, 0, 1, 2, 3, 4, 5, 6, 7);
}

// ---------------- prep: emb fp32 -> bf16
__global__ __launch_bounds__(256) void prep_emb(const float* __restrict__ emb,
                                                ushort* __restrict__ embb)
{
    int i = blockIdx.x * 256 + threadIdx.x;
    float2 v = ((const float2*)emb)[i];
    ushort2 o;
    o.x = bf16_rn(v.x);
    o.y = bf16_rn(v.y);
    ((ushort2*)embb)[i] = o;
}

// ---------------- prep: transpose+convert W0 blocks 0..2 -> Wall[3072 n][512 k] bf16
__global__ __launch_bounds__(256) void prep_wall(const float* __restrict__ ms_W0,
                                                 const float* __restrict__ sp_W0,
                                                 ushort* __restrict__ Wall)
{
    __shared__ float t[64][65];
    const int k0 = blockIdx.x * 64;   // 8
    const int n0 = blockIdx.y * 64;   // 48
    const int g = n0 >> 10;
    const float* src = (g == 0) ? ms_W0 : (sp_W0 + (size_t)(g - 1) * 512 * 1024);
    const int col0 = n0 & 1023;
    const int tr = threadIdx.x >> 6, tc = threadIdx.x & 63;
#pragma unroll
    for (int i = 0; i < 16; ++i) {
        int k = tr + i * 4;
        t[k][tc] = src[(size_t)(k0 + k) * 1024 + col0 + tc];
    }
    __syncthreads();
    const int f = threadIdx.x >> 2;
    const int c4 = threadIdx.x & 3;
    ushort tmp[16];
#pragma unroll
    for (int j = 0; j < 16; ++j) tmp[j] = bf16_rn(t[c4 * 16 + j][f]);
    uint4* dst = (uint4*)(Wall + (size_t)(n0 + f) * 512 + k0 + c4 * 16);
    dst[0] = *(uint4*)&tmp[0];
    dst[1] = *(uint4*)&tmp[8];
}

// ---------------- prep: W [k=512][f=1024] -> fragment-major (wave load = contiguous 1 KB)
__global__ __launch_bounds__(64) void prep_wfrag(const float* __restrict__ W,
                                                 ushort* __restrict__ dst_frag)
{
    const int ts = blockIdx.x;            // t*32 + s, 0..1023
    const int l = threadIdx.x;            // 0..63
    const int tt = ts >> 5, s = ts & 31;
    const int f = tt * 32 + (l & 31);
    const int kb = s * 16 + (l >> 5) * 8;
    ushort tmp[8];
#pragma unroll
    for (int j = 0; j < 8; ++j) tmp[j] = bf16_rn(W[(size_t)(kb + j) * 1024 + f]);
    uint4* dst = (uint4*)(dst_frag + ((size_t)ts * 64 + l) * 8);
    *dst = *(uint4*)&tmp[0];
}

// ---------------- H = emb @ [ms_W0 | W_src | W_ant] via MFMA (1024x512x3072)
__global__ __launch_bounds__(256) void gemm_h_mfma(
    const ushort* __restrict__ embb, const ushort* __restrict__ Wall,
    float* __restrict__ H)
{
    const int n0 = blockIdx.x * 128;  // 24
    const int m0 = blockIdx.y * 128;  // 8
    const int lane = threadIdx.x & 63, wave = threadIdx.x >> 6;
    const int wx = wave & 1, wy = wave >> 1;
    const int l15 = lane & 15, lq = lane >> 4;

    const ushort* arow[4];
#pragma unroll
    for (int mi = 0; mi < 4; ++mi)
        arow[mi] = embb + (size_t)(m0 + wy * 64 + mi * 16 + l15) * 512;
    const ushort* brow[4];
#pragma unroll
    for (int ni = 0; ni < 4; ++ni)
        brow[ni] = Wall + (size_t)(n0 + wx * 64 + ni * 16 + l15) * 512;

    f32x4 acc[4][4];
#pragma unroll
    for (int i = 0; i < 4; ++i)
#pragma unroll
        for (int j = 0; j < 4; ++j) acc[i][j] = (f32x4)0.f;

    for (int kt = 0; kt < 512; kt += 32) {
        const int ko = kt + lq * 8;
        bf16x8 av[4], bv[4];
#pragma unroll
        for (int mi = 0; mi < 4; ++mi) av[mi] = *(const bf16x8*)(arow[mi] + ko);
#pragma unroll
        for (int ni = 0; ni < 4; ++ni) bv[ni] = *(const bf16x8*)(brow[ni] + ko);
#pragma unroll
        for (int mi = 0; mi < 4; ++mi)
#pragma unroll
            for (int ni = 0; ni < 4; ++ni)
                acc[mi][ni] = __builtin_amdgcn_mfma_f32_16x16x32_bf16(av[mi], bv[ni], acc[mi][ni], 0, 0, 0);
    }
#pragma unroll
    for (int mi = 0; mi < 4; ++mi)
#pragma unroll
        for (int r = 0; r < 4; ++r) {
            int mrow = m0 + wy * 64 + mi * 16 + lq * 4 + r;
#pragma unroll
            for (int ni = 0; ni < 4; ++ni)
                H[(size_t)mrow * 3072 + n0 + wx * 64 + ni * 16 + l15] = acc[mi][ni][r];
        }
}

// ---------------- small projections
__global__ void small_proj(const float* __restrict__ speaker_emb,
                           const float* __restrict__ bucket_emb,
                           const float* __restrict__ sp_W0,
                           float* __restrict__ spk_proj, float* __restrict__ bkt_proj)
{
    int r = blockIdx.x; // 0..11
    const float* e; const float* W; float* out;
    if (r < 2) { e = speaker_emb + r * 20; W = sp_W0 + (size_t)1536 * 1024; out = spk_proj + r * 1024; }
    else       { e = bucket_emb + (r - 2) * 20; W = sp_W0 + (size_t)1556 * 1024; out = bkt_proj + (r - 2) * 1024; }
    float ek[20];
#pragma unroll
    for (int k = 0; k < 20; ++k) ek[k] = e[k];
    for (int f = threadIdx.x; f < 1024; f += blockDim.x) {
        float s = 0.f;
#pragma unroll
        for (int k = 0; k < 20; ++k) s = fmaf(ek[k], W[(size_t)k * 1024 + f], s);
        out[f] = s;
    }
}

// ---------------- mention scores
__global__ __launch_bounds__(256) void mention_score(
    const float* __restrict__ H, const float* __restrict__ ms_b0,
    const float* __restrict__ ms_W1, const float* __restrict__ ms_b1,
    float* __restrict__ ms)
{
    int m = blockIdx.x;
    float v = 0.f;
    for (int f = threadIdx.x; f < 1024; f += 256) {
        float h = H[(size_t)m * 3072 + f] + ms_b0[f];
        v += fmaxf(h, 0.f) * ms_W1[f];
    }
#pragma unroll
    for (int o = 1; o < 64; o <<= 1) v += __shfl_xor(v, o);
    __shared__ float sm[4];
    if ((threadIdx.x & 63) == 0) sm[threadIdx.x >> 6] = v;
    __syncthreads();
    if (threadIdx.x == 0) ms[m] = sm[0] + sm[1] + sm[2] + sm[3] + ms_b1[0];
}

// ---------------- pair scorer v6: ONE dispatch, grid (1024 m, 4 = chalf + 2*fh).
// 512 threads / 8 waves; round-3 body (single k-loop + gather epilogue, proven no-spill
// at runtime cbase in r4). A-tile 64 x 512 in LDS (68.6 KB) -> 2 blocks/CU.
// Changes vs r3: merged dispatch; A-build maps c = tid&63 (store banks 2-way = free,
// was 8-way); setprio(1) around MFMA quad (independent-block structure = T5's regime);
// f-half partials go to disjoint slow0/slow1 (summed in softmax_loss; no atomics/memset).
__global__ __launch_bounds__(512, 4) void pair_mfma(
    const ushort* __restrict__ embb, const ushort* __restrict__ Wfrag,
    const float* __restrict__ H, const float* __restrict__ spk_proj,
    const float* __restrict__ bkt_proj, const float* __restrict__ sp_b0,
    const float* __restrict__ sp_W1, const int* __restrict__ speaker,
    float* __restrict__ slow0, float* __restrict__ slow1)
{
    extern __shared__ ushort Alds[];                  // 64*LDSR ushorts
    float* red = (float*)(Alds + 64 * LDSR);          // 8*64 floats
    int* meta_ss = (int*)(red + 8 * 64);              // 64 ints
    int* meta_bk = meta_ss + 64;                      // 64 ints
    const int m = blockIdx.x;
    const int cbase = (blockIdx.y & 1) * 64;          // 0 or 64
    const int fh = blockIdx.y >> 1;                   // 0 or 1 (f-half)
    const int tid = threadIdx.x;
    const int spk_m = speaker[m];

    // ---- build A[c][k] = bf16(em[k]*ea[k]) in LDS + per-c metadata (64 rows)
    // lane -> row mapping: store bank = 2*(tid&63) mod 32 => 2-way aliasing (free)
    {
        const int c = tid & 63;
        const int kh = (tid >> 6) * 64;               // wave-uniform k-chunk
        int a = m - 1 - (cbase + c); if (a < 0) a = 0;
        const ushort* ea = embb + (size_t)a * 512 + kh;
        const ushort* em = embb + (size_t)m * 512 + kh;
        ushort* dst = Alds + c * LDSR + kh;
#pragma unroll
        for (int j = 0; j < 64; j += 8) {
            bf16x8 va = *(const bf16x8*)(ea + j);
            bf16x8 vm = *(const bf16x8*)(em + j);
            uint pr[4];
#pragma unroll
            for (int p = 0; p < 4; ++p) {
                float q0 = bf16_to_f((ushort)va[2 * p])     * bf16_to_f((ushort)vm[2 * p]);
                float q1 = bf16_to_f((ushort)va[2 * p + 1]) * bf16_to_f((ushort)vm[2 * p + 1]);
                pr[p] = __builtin_amdgcn_perm(__float_as_uint(q1), __float_as_uint(q0), 0x07060302u);
            }
            *(uint2*)(dst + j)     = *(uint2*)&pr[0];   // 8B stores (rows are 8B-aligned)
            *(uint2*)(dst + j + 4) = *(uint2*)&pr[2];
        }
        if (tid < 64) {                               // c == tid, a as computed above
            meta_ss[c] = (speaker[a] == spk_m) ? 1 : 0;
            int off = cbase + c + 1;                  // 1..128
            int bk;
            if (off <= 4) bk = off;
            else { bk = 31 - __clz(off) + 3; if (bk > 9) bk = 9; }
            meta_bk[c] = bk;                          // cbase=64 -> uniformly 9
        }
    }
    __syncthreads();

    const int lane = tid & 63;
    const int wave = __builtin_amdgcn_readfirstlane(tid >> 6);   // 0..7, wave-uniform
    const int l31 = lane & 31, k5 = lane >> 5;

    const int f0 = fh * 512 + wave * 64;
    // B: fragment-major; per k-step s the wave reads contiguous 1 KB per tile
    const ushort* bb = Wfrag + (size_t)(fh * 16 + wave * 2) * 16384 + (size_t)lane * 8;
    const ushort* ab = Alds + l31 * LDSR + k5 * 8;

    f32x16 acc[2][2];
#pragma unroll
    for (int i = 0; i < 2; ++i)
#pragma unroll
        for (int j = 0; j < 2; ++j) acc[i][j] = (f32x16)0.f;

#pragma unroll 2
    for (int s = 0; s < 32; ++s) {
        bf16x8 b0 = *(const bf16x8*)(bb + s * 512);
        bf16x8 b1 = *(const bf16x8*)(bb + 16384 + s * 512);
        bf16x8 a0 = ld_lds16(ab + s * 16);
        bf16x8 a1 = ld_lds16(ab + 32 * LDSR + s * 16);
        __builtin_amdgcn_s_setprio(1);
        acc[0][0] = __builtin_amdgcn_mfma_f32_32x32x16_bf16(a0, b0, acc[0][0], 0, 0, 0);
        acc[0][1] = __builtin_amdgcn_mfma_f32_32x32x16_bf16(a0, b1, acc[0][1], 0, 0, 0);
        acc[1][0] = __builtin_amdgcn_mfma_f32_32x32x16_bf16(a1, b0, acc[1][0], 0, 0, 0);
        acc[1][1] = __builtin_amdgcn_mfma_f32_32x32x16_bf16(a1, b1, acc[1][1], 0, 0, 0);
        __builtin_amdgcn_s_setprio(0);
    }

    // ---- epilogue (constants loaded here, not live during k-loop)
    float srcb[2], w1v[2], sp0v[2], sp1v[2];
#pragma unroll
    for (int ni = 0; ni < 2; ++ni) {
        int fcol = f0 + ni * 32 + l31;
        srcb[ni] = H[(size_t)m * 3072 + 1024 + fcol] + sp_b0[fcol];
        w1v[ni]  = sp_W1[fcol];
        sp0v[ni] = spk_proj[fcol];
        sp1v[ni] = spk_proj[1024 + fcol];
    }
    // C/D 32x32 layout: col=lane&31, row=(reg&3)+8*(reg>>2)+4*(lane>>5)
#pragma unroll
    for (int mi = 0; mi < 2; ++mi) {
#pragma unroll
        for (int reg = 0; reg < 16; ++reg) {
            const int c = mi * 32 + 4 * k5 + (reg & 3) + 8 * (reg >> 2);  // local
            int a = m - 1 - (cbase + c); if (a < 0) a = 0;
            const int ss = meta_ss[c];
            const int bk = meta_bk[c];
            const float* antp = H + (size_t)a * 3072 + 2048;
            float s = 0.f;
#pragma unroll
            for (int ni = 0; ni < 2; ++ni) {
                const int fcol = f0 + ni * 32 + l31;
                float bval = bkt_proj[(size_t)bk * 1024 + fcol];   // 40 KB table, L1/L2-hot
                float pre = acc[mi][ni][reg] + srcb[ni] + antp[fcol] + (ss ? sp1v[ni] : sp0v[ni]) + bval;
                s += fmaxf(pre, 0.f) * w1v[ni];
            }
            s += __shfl_xor(s, 1); s += __shfl_xor(s, 2); s += __shfl_xor(s, 4);
            s += __shfl_xor(s, 8); s += __shfl_xor(s, 16);
            if (l31 == 0) red[wave * 64 + c] = s;
        }
    }
    __syncthreads();
    if (tid < 64) {
        float s = 0.f;
#pragma unroll
        for (int i = 0; i < 8; ++i) s += red[i * 64 + tid];
        float* sout = fh ? slow1 : slow0;             // disjoint: plain store, no atomic
        sout[(size_t)m * 128 + cbase + tid] = s;
    }
}

// ---------------- softmax + per-mention loss
__device__ __forceinline__ float bsum2(float v, float* sm) {
#pragma unroll
    for (int o = 1; o < 64; o <<= 1) v += __shfl_xor(v, o);
    __syncthreads();
    if ((threadIdx.x & 63) == 0) sm[threadIdx.x >> 6] = v;
    __syncthreads();
    return sm[0] + sm[1];
}
__device__ __forceinline__ float bmax2(float v, float* sm) {
#pragma unroll
    for (int o = 1; o < 64; o <<= 1) v = fmaxf(v, __shfl_xor(v, o));
    __syncthreads();
    if ((threadIdx.x & 63) == 0) sm[threadIdx.x >> 6] = v;
    __syncthreads();
    return fmaxf(sm[0], sm[1]);
}

__global__ __launch_bounds__(128) void softmax_loss(
    const float* __restrict__ slow0, const float* __restrict__ slow1,
    const float* __restrict__ ms,
    const float* __restrict__ sp_b1, const int* __restrict__ cluster,
    float* __restrict__ out, float* __restrict__ loss_partial)
{
    const int m = blockIdx.x, c = threadIdx.x;
    __shared__ float sm[2];
    const int raw = m - 1 - c;
    const bool maskv = raw >= 0;
    const int a = maskv ? raw : 0;
    float score = slow0[(size_t)m * 128 + c] + slow1[(size_t)m * 128 + c]
                + sp_b1[0] + ms[m] + ms[a];
    if (!maskv) score = -INFINITY;

    float mx = fmaxf(bmax2(score, sm), 0.f);
    float e = expf(score - mx);
    float e0 = expf(0.f - mx);
    float sum = bsum2(e, sm) + e0;
    float p = e / sum, p0 = e0 / sum;
    const float eps = 1e-6f;
    p  = fminf(fmaxf(p,  eps), 1.f - eps);
    p0 = fminf(fmaxf(p0, eps), 1.f - eps);
    float sum2 = bsum2(p, sm) + p0;
    p /= sum2; p0 /= sum2;
    out[(size_t)m * 129 + 1 + c] = p;
    if (c == 0) out[(size_t)m * 129] = p0;

    const int cid = cluster[m];
    const bool lbl = maskv && (cid > 0) && (cluster[a] == cid);
    float anyc = bsum2(lbl ? 1.f : 0.f, sm);
    float lsum = bsum2(lbl ? -logf(p) : 0.f, sm);
    if (c == 0) {
        if (anyc == 0.f) lsum += -logf(p0);
        loss_partial[m] = lsum;
    }
}

__global__ void loss_sum(const float* __restrict__ lp, float* __restrict__ out) {
    float v = 0.f;
    for (int i = threadIdx.x; i < 1024; i += 256) v += lp[i];
#pragma unroll
    for (int o = 1; o < 64; o <<= 1) v += __shfl_xor(v, o);
    __shared__ float sm[4];
    if ((threadIdx.x & 63) == 0) sm[threadIdx.x >> 6] = v;
    __syncthreads();
    if (threadIdx.x == 0) out[(size_t)1024 * 129] = sm[0] + sm[1] + sm[2] + sm[3];
}

extern "C" void kernel_launch(void* const* d_in, const int* in_sizes, int n_in,
                              void* d_out, int out_size, void* d_ws, size_t ws_size,
                              hipStream_t stream)
{
    const float* emb   = (const float*)d_in[0];
    const int*   clus  = (const int*)  d_in[1];
    const int*   spk   = (const int*)  d_in[2];
    const float* ms_W0 = (const float*)d_in[3];
    const float* ms_b0 = (const float*)d_in[4];
    const float* ms_W1 = (const float*)d_in[5];
    const float* ms_b1 = (const float*)d_in[6];
    const float* sp_W0 = (const float*)d_in[7];
    const float* sp_b0 = (const float*)d_in[8];
    const float* sp_W1 = (const float*)d_in[9];
    const float* sp_b1 = (const float*)d_in[10];
    const float* spke  = (const float*)d_in[11];
    const float* bkte  = (const float*)d_in[12];

    float* ws = (float*)d_ws;
    float* H        = ws;
    float* slow0    = ws + 3145728;
    float* spk_proj = ws + 3276800;
    float* bkt_proj = ws + 3278848;
    float* msc      = ws + 3289088;
    float* lossp    = ws + 3290112;
    ushort* embb    = (ushort*)(ws + 3291136);
    ushort* Wall    = (ushort*)(ws + 3553280);
    ushort* Wfrag   = Wall + (size_t)3072 * 512;   // reuse W_prod region, frag-major
    float* slow1    = ws + 4601856;                // after Wall region
    float* out = (float*)d_out;

    const int pair_lds = 64 * LDSR * 2 + 8 * 64 * 4 + 2 * 64 * 4;   // 68608 B

    static bool attr_set = false;
    if (!attr_set) {
        hipFuncSetAttribute((const void*)&pair_mfma,
                            hipFuncAttributeMaxDynamicSharedMemorySize,
                            pair_lds);
        attr_set = true;
    }

    hipLaunchKernelGGL(prep_emb, dim3(1024), dim3(256), 0, stream, emb, embb);
    hipLaunchKernelGGL(prep_wall, dim3(8, 48), dim3(256), 0, stream, ms_W0, sp_W0, Wall);
    hipLaunchKernelGGL(prep_wfrag, dim3(1024), dim3(64), 0, stream,
                       sp_W0 + (size_t)1024 * 1024, Wfrag);     // W_prod
    hipLaunchKernelGGL(gemm_h_mfma, dim3(24, 8), dim3(256), 0, stream, embb, Wall, H);
    hipLaunchKernelGGL(small_proj, dim3(12), dim3(256), 0, stream, spke, bkte, sp_W0, spk_proj, bkt_proj);
    hipLaunchKernelGGL(mention_score, dim3(1024), dim3(256), 0, stream, H, ms_b0, ms_W1, ms_b1, msc);
    hipLaunchKernelGGL(pair_mfma, dim3(1024, 4), dim3(512), pair_lds, stream,
                       embb, Wfrag, H, spk_proj, bkt_proj, sp_b0, sp_W1, spk, slow0, slow1);
    hipLaunchKernelGGL(softmax_loss, dim3(1024), dim3(128), 0, stream,
                       slow0, slow1, msc, sp_b1, clus, out, lossp);
    hipLaunchKernelGGL(loss_sum, dim3(1), dim3(256), 0, stream, lossp, out);
}